// Round 1
// baseline (10094.392 us; speedup 1.0000x reference)
//
#include <hip/hip_runtime.h>
#include <cstdint>
#include <cstddef>

// ---------------------------------------------------------------------------
// LSTM forward, persistent-kernel design:
//   grid = 256 WGs = 4 batch-groups(16 rows) x 64 hidden-groups(16 cols)
//   W (2048x4096) transposed->bf16, held in REGISTERS (B-fragments) per wave
//   waves 0-3: x-part partials (K 0..1023)   -- overlap with barrier spin
//   waves 4-7: h-part partials (K 1024..2047) after 64-WG release/acquire barrier
//   LDS: 8x4 partial C tiles (16x16 fp32, padded col stride) -> fused epilogue
//   c-state lives in thread registers across all 512 steps
// ---------------------------------------------------------------------------

typedef short bf16x8 __attribute__((ext_vector_type(8)));
typedef float f32x4  __attribute__((ext_vector_type(4)));

#define XT_OFF   0ull                 // x^T bf16 [512][64][1024]  = 64 MiB
#define WT_OFF   67108864ull          // W^T bf16 [4096][2048]     = 16 MiB
#define HB_OFF   83886080ull          // h double buffer bf16 [2][64][1024] = 256 KiB
#define CNT_OFF  84148224ull          // 256 uints (4 used, spaced 256B)
#define WS_NEED  84149248ull

__device__ __forceinline__ unsigned short f2bf(float f) {
  union { float f; unsigned u; } v; v.f = f;
  unsigned r = (v.u + 0x7fffu + ((v.u >> 16) & 1u)) >> 16;   // RNE
  return (unsigned short)r;
}

// x (B,S,I) fp32 -> xT (S,B,I) bf16.  blk = b*512+s, 256 thr x float4
__global__ void k_convert_x(const float* __restrict__ x, unsigned short* __restrict__ xT) {
  const int blk = blockIdx.x;
  const int b = blk >> 9, s = blk & 511;
  const float4 v = ((const float4*)(x + (size_t)blk * 1024))[threadIdx.x];
  ushort4 o;
  o.x = f2bf(v.x); o.y = f2bf(v.y); o.z = f2bf(v.z); o.w = f2bf(v.w);
  ((ushort4*)(xT + ((size_t)s * 64 + b) * 1024))[threadIdx.x] = o;
}

// W [2048][4096] fp32 -> WT [4096][2048] bf16, 64x64 LDS tiles
__global__ void k_convert_W(const float* __restrict__ W, unsigned short* __restrict__ WT) {
  __shared__ float tile[64][65];
  const int bx = blockIdx.x & 31;   // k-tile
  const int by = blockIdx.x >> 5;   // g-tile
  const int k0 = bx << 6, g0 = by << 6;
  for (int i = threadIdx.x; i < 4096; i += 256) {
    const int r = i >> 6, c = i & 63;
    tile[r][c] = W[(size_t)(k0 + r) * 4096 + g0 + c];
  }
  __syncthreads();
  for (int i = threadIdx.x; i < 4096; i += 256) {
    const int g = i >> 6, k = i & 63;
    WT[(size_t)(g0 + g) * 2048 + k0 + k] = f2bf(tile[k][g]);
  }
}

// zero h parity-0 buffer (131072 B) + barrier counters
__global__ void k_init(unsigned short* __restrict__ hbuf, unsigned int* __restrict__ cnt) {
  const size_t i = (size_t)blockIdx.x * 256 + threadIdx.x;
  ((uint4*)hbuf)[i] = uint4{0u, 0u, 0u, 0u};
  if (blockIdx.x == 0) cnt[threadIdx.x] = 0u;
}

__device__ __forceinline__ void mfma_block(const unsigned short* __restrict__ ap,
                                           const bf16x8 Bf[4][8],
                                           float* __restrict__ sb) {
  bf16x8 A[8];
#pragma unroll
  for (int kc = 0; kc < 8; ++kc) A[kc] = *(const bf16x8*)(ap + kc * 32);
  f32x4 a0 = {0.f, 0.f, 0.f, 0.f};
  f32x4 a1 = a0, a2 = a0, a3 = a0;
#pragma unroll
  for (int kc = 0; kc < 8; ++kc) {
    a0 = __builtin_amdgcn_mfma_f32_16x16x32_bf16(A[kc], Bf[0][kc], a0, 0, 0, 0);
    a1 = __builtin_amdgcn_mfma_f32_16x16x32_bf16(A[kc], Bf[1][kc], a1, 0, 0, 0);
    a2 = __builtin_amdgcn_mfma_f32_16x16x32_bf16(A[kc], Bf[2][kc], a2, 0, 0, 0);
    a3 = __builtin_amdgcn_mfma_f32_16x16x32_bf16(A[kc], Bf[3][kc], a3, 0, 0, 0);
  }
  // C layout: col=lane&15, row=(lane>>4)*4+reg  -> store [col][row] (stride 20 floats, 2-way bank max)
  *(f32x4*)(sb + 0)   = a0;
  *(f32x4*)(sb + 320) = a1;
  *(f32x4*)(sb + 640) = a2;
  *(f32x4*)(sb + 960) = a3;
}

__global__ __launch_bounds__(512, 1) void lstm_persistent(
    const unsigned short* __restrict__ xT,   // [512][64][1024] bf16
    const unsigned short* __restrict__ WT,   // [4096][2048] bf16
    const float* __restrict__ bias,          // [4096]
    unsigned short* __restrict__ hbuf,       // [2][64][1024] bf16
    unsigned int* __restrict__ cnt,          // per-bg counters (stride 64 uints)
    float* __restrict__ out)                 // outputs(B,S,H) + h_T + c_T
{
  __shared__ float slots[8 * 4 * 320];       // [wave][gate][col*20 + row], 40 KiB

  const int tid  = threadIdx.x;
  const int lane = tid & 63;
  const int wave = tid >> 6;                 // 0..7, K-slice = wave*256
  const int bg = blockIdx.x & 3;             // batch group (16 rows)
  const int hg = blockIdx.x >> 2;            // hidden group (16 cols)
  const int b0 = bg << 4;
  const int l15 = lane & 15;
  const int l4  = lane >> 4;

  // --- loop-invariant B fragments: 4 gates x 8 k-chunks, 128 VGPRs/wave ---
  bf16x8 Bf[4][8];
  {
    const int kb = wave * 256;               // waves 0-3 -> Wx rows, 4-7 -> Wh rows
#pragma unroll
    for (int g = 0; g < 4; ++g) {
      const unsigned short* wp =
          WT + (size_t)(g * 1024 + (hg << 4) + l15) * 2048 + kb + l4 * 8;
#pragma unroll
      for (int kc = 0; kc < 8; ++kc) Bf[g][kc] = *(const bf16x8*)(wp + kc * 32);
    }
  }

  // --- per-cell epilogue constants (threads 0..255: cell (row rb, col cc)) ---
  const int cc = tid & 15;
  const int rb = (tid >> 4) & 15;
  float bi = 0.f, bff = 0.f, bgg = 0.f, bo = 0.f;
  if (tid < 256) {
    const int col = (hg << 4) + cc;
    bi  = bias[col];
    bff = bias[1024 + col];
    bgg = bias[2048 + col];
    bo  = bias[3072 + col];
  }
  float c_state = 0.f;
  unsigned int* myCnt = cnt + bg * 64;

  const unsigned short* xb = xT + (size_t)(b0 + l15) * 1024 + wave * 256 + l4 * 8;
  const unsigned short* hb = hbuf + (size_t)(b0 + l15) * 1024 + (wave - 4) * 256 + l4 * 8;
  unsigned short* hw = hbuf + (size_t)(b0 + rb) * 1024 + (hg << 4) + cc;
  float* outp = out + (size_t)(b0 + rb) * 512 * 1024 + (hg << 4) + cc;
  float* sb = &slots[(wave * 4) * 320 + l15 * 20 + l4 * 4];

#pragma unroll 1
  for (int t = 0; t < 512; ++t) {
    const int par = t & 1;
    if (wave < 4) {
      // x-part partials for step t: runs concurrently with waves 4-7's spin
      mfma_block(xb + (size_t)t * 65536, Bf, sb);
    } else {
      if (t > 0) {
        const unsigned int tgt = (unsigned int)t * 64u;
        int guard = 0;
        while (__hip_atomic_load(myCnt, __ATOMIC_RELAXED, __HIP_MEMORY_SCOPE_AGENT) < tgt) {
          if (++guard > (1 << 26)) break;    // anti-hang safety; never expected
        }
        __builtin_amdgcn_fence(__ATOMIC_ACQUIRE, "agent");
      }
      // h-part partials from h(t) (parity buffer)
      mfma_block(hb + (size_t)par * 65536, Bf, sb);
    }
    __syncthreads();   // partials complete

    if (tid < 256) {
      float Gi = bi, Gf = bff, Gg = bgg, Go = bo;
      const int base = cc * 20 + rb;
#pragma unroll
      for (int w = 0; w < 8; ++w) {
        Gi += slots[(w * 4 + 0) * 320 + base];
        Gf += slots[(w * 4 + 1) * 320 + base];
        Gg += slots[(w * 4 + 2) * 320 + base];
        Go += slots[(w * 4 + 3) * 320 + base];
      }
      const float ig = 1.f / (1.f + __expf(-Gi));
      const float fg = 1.f / (1.f + __expf(-Gf));
      const float og = 1.f / (1.f + __expf(-Go));
      float ag = __builtin_fabsf(Gg);
      float eg = __expf(-2.f * ag);
      float tg = (1.f - eg) / (1.f + eg);
      tg = (Gg < 0.f) ? -tg : tg;
      c_state = fg * c_state + ig * tg;
      float ac = __builtin_fabsf(c_state);
      float ec = __expf(-2.f * ac);
      float tc = (1.f - ec) / (1.f + ec);
      tc = (c_state < 0.f) ? -tc : tc;
      const float h = og * tc;
      outp[(size_t)t * 1024] = h;                 // outputs[b][t][col]
      hw[(size_t)(par ^ 1) * 65536] = f2bf(h);    // h(t+1) into other parity
      if (t == 511) {
        const size_t o2 = 33554432ull + (size_t)(b0 + rb) * 1024 + (hg << 4) + cc;
        out[o2] = h;                              // h_T
        out[o2 + 65536] = c_state;                // c_T
      }
    }
    __syncthreads();   // epilogue (slot reads + h writes) complete

    if (tid == 0) {
      __builtin_amdgcn_fence(__ATOMIC_RELEASE, "agent");   // L2 writeback of h(t+1)
      __hip_atomic_fetch_add(myCnt, 1u, __ATOMIC_RELAXED, __HIP_MEMORY_SCOPE_AGENT);
    }
  }
}

extern "C" void kernel_launch(void* const* d_in, const int* in_sizes, int n_in,
                              void* d_out, int out_size, void* d_ws, size_t ws_size,
                              hipStream_t stream) {
  const float* x = (const float*)d_in[0];   // (64,512,1024)
  const float* W = (const float*)d_in[1];   // (2048,4096)
  const float* b = (const float*)d_in[2];   // (4096,)
  float* out = (float*)d_out;
  char* ws = (char*)d_ws;
  if (ws_size < WS_NEED) return;            // need ~84.2 MB scratch

  unsigned short* xT = (unsigned short*)(ws + XT_OFF);
  unsigned short* WT = (unsigned short*)(ws + WT_OFF);
  unsigned short* hb = (unsigned short*)(ws + HB_OFF);
  unsigned int*  cn = (unsigned int*)(ws + CNT_OFF);

  hipLaunchKernelGGL(k_convert_x, dim3(32768), dim3(256), 0, stream, x, xT);
  hipLaunchKernelGGL(k_convert_W, dim3(2048),  dim3(256), 0, stream, W, WT);
  hipLaunchKernelGGL(k_init,      dim3(32),    dim3(256), 0, stream, hb, cn);

  void* kargs[] = { (void*)&xT, (void*)&WT, (void*)&b, (void*)&hb, (void*)&cn, (void*)&out };
  hipLaunchCooperativeKernel((void*)lstm_persistent, dim3(256), dim3(512),
                             kargs, 0, stream);
}

// Round 2
// 2377.252 us; speedup vs baseline: 4.2462x; 4.2462x over previous
//
#include <hip/hip_runtime.h>
#include <cstdint>
#include <cstddef>

// ---------------------------------------------------------------------------
// LSTM forward, persistent-kernel design (round 2):
//   grid = 256 WGs = 4 batch-groups(16 rows) x 64 hidden-groups(16 cols)
//   W (2048x4096) transposed->bf16, held in REGISTERS (B-fragments) per wave
//   waves 0-3: x-part partials (K 0..1023)   -- overlap with barrier spin
//   waves 4-7: h-part partials (K 1024..2047) after 64-WG counter barrier
//   Cross-WG h traffic + counters use sc0|sc1 cache-BYPASS accesses (coherent
//   at Infinity Cache) -> NO agent fences -> no per-step L2 wb/inv (round-1
//   bottleneck: 20us/step of buffer_wbl2/buffer_inv).
//   LDS: 8x4 partial C tiles (16x16 fp32, padded col stride) -> fused epilogue
//   c-state lives in thread registers across all 512 steps
// ---------------------------------------------------------------------------

typedef short bf16x8 __attribute__((ext_vector_type(8)));
typedef float f32x4  __attribute__((ext_vector_type(4)));
typedef int   i32x4  __attribute__((ext_vector_type(4)));

#define XT_OFF   0ull                 // x^T bf16 [512][64][1024]  = 64 MiB
#define WT_OFF   67108864ull          // W^T bf16 [4096][2048]     = 16 MiB
#define HB_OFF   83886080ull          // h double buffer bf16 [2][64][1024] = 256 KiB
#define CNT_OFF  84148224ull          // 256 uints (4 used, spaced 256B)
#define WS_NEED  84149248ull

__device__ __forceinline__ unsigned short f2bf(float f) {
  union { float f; unsigned u; } v; v.f = f;
  unsigned r = (v.u + 0x7fffu + ((v.u >> 16) & 1u)) >> 16;   // RNE
  return (unsigned short)r;
}

// x (B,S,I) fp32 -> xT (S,B,I) bf16.  blk = b*512+s, 256 thr x float4
__global__ void k_convert_x(const float* __restrict__ x, unsigned short* __restrict__ xT) {
  const int blk = blockIdx.x;
  const int b = blk >> 9, s = blk & 511;
  const float4 v = ((const float4*)(x + (size_t)blk * 1024))[threadIdx.x];
  ushort4 o;
  o.x = f2bf(v.x); o.y = f2bf(v.y); o.z = f2bf(v.z); o.w = f2bf(v.w);
  ((ushort4*)(xT + ((size_t)s * 64 + b) * 1024))[threadIdx.x] = o;
}

// W [2048][4096] fp32 -> WT [4096][2048] bf16, 64x64 LDS tiles
__global__ void k_convert_W(const float* __restrict__ W, unsigned short* __restrict__ WT) {
  __shared__ float tile[64][65];
  const int bx = blockIdx.x & 31;   // k-tile
  const int by = blockIdx.x >> 5;   // g-tile
  const int k0 = bx << 6, g0 = by << 6;
  for (int i = threadIdx.x; i < 4096; i += 256) {
    const int r = i >> 6, c = i & 63;
    tile[r][c] = W[(size_t)(k0 + r) * 4096 + g0 + c];
  }
  __syncthreads();
  for (int i = threadIdx.x; i < 4096; i += 256) {
    const int g = i >> 6, k = i & 63;
    WT[(size_t)(g0 + g) * 2048 + k0 + k] = f2bf(tile[k][g]);
  }
}

// zero h parity-0 buffer (131072 B) + barrier counters
__global__ void k_init(unsigned short* __restrict__ hbuf, unsigned int* __restrict__ cnt) {
  const size_t i = (size_t)blockIdx.x * 256 + threadIdx.x;
  ((uint4*)hbuf)[i] = uint4{0u, 0u, 0u, 0u};
  if (blockIdx.x == 0) cnt[threadIdx.x] = 0u;
}

// ---- cached-path MFMA block (x side; xT is immutable, L2-friendly) ----
__device__ __forceinline__ void mfma_block(const unsigned short* __restrict__ ap,
                                           const bf16x8 Bf[4][8],
                                           float* __restrict__ sb) {
  bf16x8 A[8];
#pragma unroll
  for (int kc = 0; kc < 8; ++kc) A[kc] = *(const bf16x8*)(ap + kc * 32);
  f32x4 a0 = {0.f, 0.f, 0.f, 0.f};
  f32x4 a1 = a0, a2 = a0, a3 = a0;
#pragma unroll
  for (int kc = 0; kc < 8; ++kc) {
    a0 = __builtin_amdgcn_mfma_f32_16x16x32_bf16(A[kc], Bf[0][kc], a0, 0, 0, 0);
    a1 = __builtin_amdgcn_mfma_f32_16x16x32_bf16(A[kc], Bf[1][kc], a1, 0, 0, 0);
    a2 = __builtin_amdgcn_mfma_f32_16x16x32_bf16(A[kc], Bf[2][kc], a2, 0, 0, 0);
    a3 = __builtin_amdgcn_mfma_f32_16x16x32_bf16(A[kc], Bf[3][kc], a3, 0, 0, 0);
  }
  *(f32x4*)(sb + 0)   = a0;
  *(f32x4*)(sb + 320) = a1;
  *(f32x4*)(sb + 640) = a2;
  *(f32x4*)(sb + 960) = a3;
}

// ---- cache-BYPASS MFMA block (h side; fresh data from Infinity Cache) ----
__device__ __forceinline__ void mfma_block_bypass(const unsigned short* __restrict__ ap,
                                                  const bf16x8 Bf[4][8],
                                                  float* __restrict__ sb) {
  union frag_u { i32x4 i; bf16x8 h; } A[8];
#pragma unroll
  for (int kc = 0; kc < 8; ++kc) {
    asm volatile("global_load_dwordx4 %0, %1, off sc0 sc1"
                 : "=v"(A[kc].i) : "v"(ap + kc * 32) : "memory");
  }
  // data-chained waitcnt: forces every consumer of A[] after the wait
  asm volatile("s_waitcnt vmcnt(0)"
               : "+v"(A[0].i), "+v"(A[1].i), "+v"(A[2].i), "+v"(A[3].i),
                 "+v"(A[4].i), "+v"(A[5].i), "+v"(A[6].i), "+v"(A[7].i)
               :: "memory");
  f32x4 a0 = {0.f, 0.f, 0.f, 0.f};
  f32x4 a1 = a0, a2 = a0, a3 = a0;
#pragma unroll
  for (int kc = 0; kc < 8; ++kc) {
    a0 = __builtin_amdgcn_mfma_f32_16x16x32_bf16(A[kc].h, Bf[0][kc], a0, 0, 0, 0);
    a1 = __builtin_amdgcn_mfma_f32_16x16x32_bf16(A[kc].h, Bf[1][kc], a1, 0, 0, 0);
    a2 = __builtin_amdgcn_mfma_f32_16x16x32_bf16(A[kc].h, Bf[2][kc], a2, 0, 0, 0);
    a3 = __builtin_amdgcn_mfma_f32_16x16x32_bf16(A[kc].h, Bf[3][kc], a3, 0, 0, 0);
  }
  *(f32x4*)(sb + 0)   = a0;
  *(f32x4*)(sb + 320) = a1;
  *(f32x4*)(sb + 640) = a2;
  *(f32x4*)(sb + 960) = a3;
}

__global__ __launch_bounds__(512, 1) void lstm_persistent(
    const unsigned short* __restrict__ xT,   // [512][64][1024] bf16
    const unsigned short* __restrict__ WT,   // [4096][2048] bf16
    const float* __restrict__ bias,          // [4096]
    unsigned short* __restrict__ hbuf,       // [2][64][1024] bf16
    unsigned int* __restrict__ cnt,          // per-bg counters (stride 64 uints)
    float* __restrict__ out)                 // outputs(B,S,H) + h_T + c_T
{
  __shared__ float slots[8 * 4 * 320];       // [wave][gate][col*20 + row], 40 KiB

  const int tid  = threadIdx.x;
  const int lane = tid & 63;
  const int wave = tid >> 6;                 // 0..7, K-slice = wave*256
  const int bg = blockIdx.x & 3;             // batch group (16 rows)
  const int hg = blockIdx.x >> 2;            // hidden group (16 cols)
  const int b0 = bg << 4;
  const int l15 = lane & 15;
  const int l4  = lane >> 4;

  // --- loop-invariant B fragments: 4 gates x 8 k-chunks, 128 VGPRs/wave ---
  bf16x8 Bf[4][8];
  {
    const int kb = wave * 256;               // waves 0-3 -> Wx rows, 4-7 -> Wh rows
#pragma unroll
    for (int g = 0; g < 4; ++g) {
      const unsigned short* wp =
          WT + (size_t)(g * 1024 + (hg << 4) + l15) * 2048 + kb + l4 * 8;
#pragma unroll
      for (int kc = 0; kc < 8; ++kc) Bf[g][kc] = *(const bf16x8*)(wp + kc * 32);
    }
  }

  // --- per-cell epilogue constants (threads 0..255: cell (row rb, col cc)) ---
  const int cc = tid & 15;
  const int rb = (tid >> 4) & 15;
  float bi = 0.f, bff = 0.f, bgg = 0.f, bo = 0.f;
  if (tid < 256) {
    const int col = (hg << 4) + cc;
    bi  = bias[col];
    bff = bias[1024 + col];
    bgg = bias[2048 + col];
    bo  = bias[3072 + col];
  }
  float c_state = 0.f;
  unsigned int* myCnt = cnt + bg * 64;

  const unsigned short* xb = xT + (size_t)(b0 + l15) * 1024 + wave * 256 + l4 * 8;
  const unsigned short* hb = hbuf + (size_t)(b0 + l15) * 1024 + (wave - 4) * 256 + l4 * 8;
  unsigned short* hw = hbuf + (size_t)(b0 + rb) * 1024 + (hg << 4) + cc;
  float* outp = out + (size_t)(b0 + rb) * 512 * 1024 + (hg << 4) + cc;
  float* sb = &slots[(wave * 4) * 320 + l15 * 20 + l4 * 4];

#pragma unroll 1
  for (int t = 0; t < 512; ++t) {
    const int par = t & 1;
    if (wave < 4) {
      // x-part partials for step t: runs concurrently with waves 4-7's spin
      mfma_block(xb + (size_t)t * 65536, Bf, sb);
    } else {
      if (t > 0) {
        const unsigned int tgt = (unsigned int)t * 64u;
        long guard = 0;
        while (__hip_atomic_load(myCnt, __ATOMIC_RELAXED, __HIP_MEMORY_SCOPE_AGENT) < tgt) {
          if (++guard > (1l << 27)) break;   // anti-hang safety; never expected
        }
      }
      // h-part partials from h(t) (parity buffer), cache-bypass loads
      mfma_block_bypass(hb + (size_t)par * 65536, Bf, sb);
    }
    __syncthreads();   // partials complete

    float hval = 0.f;
    if (tid < 256) {
      float Gi = bi, Gf = bff, Gg = bgg, Go = bo;
      const int base = cc * 20 + rb;
#pragma unroll
      for (int w = 0; w < 8; ++w) {
        Gi += slots[(w * 4 + 0) * 320 + base];
        Gf += slots[(w * 4 + 1) * 320 + base];
        Gg += slots[(w * 4 + 2) * 320 + base];
        Go += slots[(w * 4 + 3) * 320 + base];
      }
      const float ig = 1.f / (1.f + __expf(-Gi));
      const float fg = 1.f / (1.f + __expf(-Gf));
      const float og = 1.f / (1.f + __expf(-Go));
      float ag = __builtin_fabsf(Gg);
      float eg = __expf(-2.f * ag);
      float tg = (1.f - eg) / (1.f + eg);
      tg = (Gg < 0.f) ? -tg : tg;
      c_state = fg * c_state + ig * tg;
      float ac = __builtin_fabsf(c_state);
      float ec = __expf(-2.f * ac);
      float tc = (1.f - ec) / (1.f + ec);
      tc = (c_state < 0.f) ? -tc : tc;
      hval = og * tc;
      // h(t+1) -> other parity slab, cache-bypass (visible at IC; no fence)
      unsigned int hbits = (unsigned int)f2bf(hval);
      asm volatile("global_store_short %0, %1, off sc0 sc1"
                   :: "v"(hw + (size_t)(par ^ 1) * 65536), "v"(hbits) : "memory");
    }
    __syncthreads();   // h stores drained (vmcnt(0) before s_barrier) + slots consumed

    if (tid == 0) {
      // all 512 threads' h stores are at IC -> plain relaxed bump, no fence
      __hip_atomic_fetch_add(myCnt, 1u, __ATOMIC_RELAXED, __HIP_MEMORY_SCOPE_AGENT);
    }
    if (tid < 256) {
      outp[(size_t)t * 1024] = hval;              // off critical path now
      if (t == 511) {
        const size_t o2 = 33554432ull + (size_t)(b0 + rb) * 1024 + (hg << 4) + cc;
        out[o2] = hval;                           // h_T
        out[o2 + 65536] = c_state;                // c_T
      }
    }
  }
}

extern "C" void kernel_launch(void* const* d_in, const int* in_sizes, int n_in,
                              void* d_out, int out_size, void* d_ws, size_t ws_size,
                              hipStream_t stream) {
  const float* x = (const float*)d_in[0];   // (64,512,1024)
  const float* W = (const float*)d_in[1];   // (2048,4096)
  const float* b = (const float*)d_in[2];   // (4096,)
  float* out = (float*)d_out;
  char* ws = (char*)d_ws;
  if (ws_size < WS_NEED) return;            // need ~84.2 MB scratch

  unsigned short* xT = (unsigned short*)(ws + XT_OFF);
  unsigned short* WT = (unsigned short*)(ws + WT_OFF);
  unsigned short* hb = (unsigned short*)(ws + HB_OFF);
  unsigned int*  cn = (unsigned int*)(ws + CNT_OFF);

  hipLaunchKernelGGL(k_convert_x, dim3(32768), dim3(256), 0, stream, x, xT);
  hipLaunchKernelGGL(k_convert_W, dim3(2048),  dim3(256), 0, stream, W, WT);
  hipLaunchKernelGGL(k_init,      dim3(32),    dim3(256), 0, stream, hb, cn);

  void* kargs[] = { (void*)&xT, (void*)&WT, (void*)&b, (void*)&hb, (void*)&cn, (void*)&out };
  hipLaunchCooperativeKernel((void*)lstm_persistent, dim3(256), dim3(512),
                             kargs, 0, stream);
}